// Round 1
// baseline (603.620 us; speedup 1.0000x reference)
//
#include <hip/hip_runtime.h>

typedef __bf16 bf16x8 __attribute__((ext_vector_type(8)));
typedef short short8 __attribute__((ext_vector_type(8)));
typedef float f32x4 __attribute__((ext_vector_type(4)));
typedef unsigned short ushort_t;

// ---------- helpers ----------
__device__ __forceinline__ ushort_t f2bf(float f) {
  union { float f; unsigned u; } v; v.f = f;
  unsigned r = v.u + 0x7fffu + ((v.u >> 16) & 1u);   // RNE
  return (ushort_t)(r >> 16);
}

__device__ __forceinline__ void g2lds16(const void* g, void* l) {
  __builtin_amdgcn_global_load_lds(
      (const __attribute__((address_space(1))) void*)g,
      (__attribute__((address_space(3))) void*)l, 16, 0, 0);
}

template<int CTRL>
__device__ __forceinline__ float dpp_step(float x) {
  int t = __builtin_amdgcn_update_dpp(0, __float_as_int(x), CTRL, 0xf, 0xf, false);
  return x + __int_as_float(t);
}
// full 64-lane sum; result valid on lane 63
__device__ __forceinline__ float wave_sum64(float v) {
  v = dpp_step<0x111>(v);  // row_shr:1
  v = dpp_step<0x112>(v);  // row_shr:2
  v = dpp_step<0x114>(v);  // row_shr:4
  v = dpp_step<0x118>(v);  // row_shr:8
  v = dpp_step<0x142>(v);  // row_bcast:15
  v = dpp_step<0x143>(v);  // row_bcast:31
  return v;
}

// ---------- conversion / transpose ----------
__global__ __launch_bounds__(256) void conv_f32_bf16(const float* __restrict__ in,
                                                     ushort_t* __restrict__ outp) {
  int i = (blockIdx.x * 256 + threadIdx.x) * 4;
  float4 v = *(const float4*)(in + i);
  union { ushort_t u[4]; uint2 v2; } o;
  o.u[0] = f2bf(v.x); o.u[1] = f2bf(v.y); o.u[2] = f2bf(v.z); o.u[3] = f2bf(v.w);
  *(uint2*)(outp + i) = o.v2;
}

// W [K][N] f32 -> Wt [N][K] bf16
__global__ __launch_bounds__(256) void transpose_kernel(const float* __restrict__ W,
                                                        ushort_t* __restrict__ Wt,
                                                        int K, int N) {
  __shared__ float tile[32][33];
  const int n0 = blockIdx.x * 32, k0 = blockIdx.y * 32;
  const int tx = threadIdx.x & 31, ty = threadIdx.x >> 5;  // 32x8
#pragma unroll
  for (int r = 0; r < 32; r += 8)
    tile[ty + r][tx] = W[(size_t)(k0 + ty + r) * N + n0 + tx];
  __syncthreads();
#pragma unroll
  for (int r = 0; r < 32; r += 8)
    Wt[(size_t)(n0 + ty + r) * K + k0 + tx] = f2bf(tile[tx][ty + r]);
}

// ---------- bf16 MFMA GEMM (m97 structure: 128x128 tile, BK=32, 4 waves) ----------
// A [M][K] bf16 row-major; Bt [N][K] bf16 row-major (i.e. B^T). C = A*B.
// MODE 0: N=3072, n<1536 -> xs=silu(v) (f32 out0 + bf16 out1); n>=1536 -> sres=silu(v) (out2)
// MODE 1: out0 = v, ldc=1664
// MODE 2: out0 = v + resid, ldc=768
template<int MODE>
__global__ __launch_bounds__(256)
void gemm_bf16(const ushort_t* __restrict__ A, const ushort_t* __restrict__ Bt,
               const int K, float* __restrict__ out0, ushort_t* __restrict__ out1,
               float* __restrict__ out2, const float* __restrict__ resid) {
  __shared__ __align__(16) ushort_t Asl[128 * 32];
  __shared__ __align__(16) ushort_t Bsl[128 * 32];
  const int tid = threadIdx.x;
  const int lane = tid & 63;
  const int wid = tid >> 6;
  const int wm = wid >> 1, wn = wid & 1;
  const int lr = lane & 15, lk = lane >> 4;
  const int bm = blockIdx.y, bn = blockIdx.x;
  const ushort_t* Ab = A + (size_t)bm * 128 * K;
  const ushort_t* Bb = Bt + (size_t)bn * 128 * K;

  f32x4 acc[4][4];
#pragma unroll
  for (int i = 0; i < 4; ++i)
#pragma unroll
    for (int j = 0; j < 4; ++j) acc[i][j] = (f32x4){0.f, 0.f, 0.f, 0.f};

  for (int k0 = 0; k0 < K; k0 += 32) {
    // stage 128x32 A-tile and 128x32 Bt-tile; LDS dest wave-uniform base + lane*16
#pragma unroll
    for (int it = 0; it < 2; ++it) {
      const int cb = ((it << 2) + wid) << 6;   // wave-uniform chunk base
      const int ch = cb + lane;
      const int row = ch >> 2;
      const int c8 = (ch & 3) << 3;
      g2lds16(Ab + (size_t)row * K + k0 + c8, Asl + (size_t)cb * 8);
      g2lds16(Bb + (size_t)row * K + k0 + c8, Bsl + (size_t)cb * 8);
    }
    __syncthreads();
    short8 av[4], bv[4];
#pragma unroll
    for (int i = 0; i < 4; ++i)
      av[i] = *(const short8*)(Asl + ((wm * 64 + i * 16 + lr) * 32 + lk * 8));
#pragma unroll
    for (int j = 0; j < 4; ++j)
      bv[j] = *(const short8*)(Bsl + ((wn * 64 + j * 16 + lr) * 32 + lk * 8));
#pragma unroll
    for (int i = 0; i < 4; ++i)
#pragma unroll
      for (int j = 0; j < 4; ++j)
        acc[i][j] = __builtin_amdgcn_mfma_f32_16x16x32_bf16(
            __builtin_bit_cast(bf16x8, av[i]), __builtin_bit_cast(bf16x8, bv[j]),
            acc[i][j], 0, 0, 0);
    __syncthreads();
  }

  const int mb = bm * 128 + wm * 64 + (lane >> 4) * 4;
  const int nb = bn * 128 + wn * 64 + (lane & 15);
#pragma unroll
  for (int i = 0; i < 4; ++i) {
#pragma unroll
    for (int j = 0; j < 4; ++j) {
      const int n = nb + j * 16;
#pragma unroll
      for (int r = 0; r < 4; ++r) {
        const int m = mb + i * 16 + r;
        float v = acc[i][j][r];
        if (MODE == 0) {
          float sv = v / (1.f + __expf(-v));   // silu
          if (n < 1536) {
            out0[(size_t)m * 1536 + n] = sv;
            out1[(size_t)m * 1536 + n] = f2bf(sv);
          } else {
            out2[(size_t)m * 1536 + (n - 1536)] = sv;
          }
        } else if (MODE == 1) {
          out0[(size_t)m * 1664 + n] = v;
        } else {
          const size_t id = (size_t)m * 768 + n;
          out0[id] = v + resid[id];
        }
      }
    }
  }
}

// ---------- delta GEMM (K=64) + softplus + clamp ----------
__global__ __launch_bounds__(256)
void dt_gemm(const float* __restrict__ xdbl, const float* __restrict__ Wdt,
             const float* __restrict__ bdt, float* __restrict__ delta) {
  __shared__ float Wl[64][256];
  __shared__ float Xl[32][64];
  const int tid = threadIdx.x;
  const int n0 = blockIdx.x << 8;
  const int m0 = blockIdx.y << 5;
  for (int i = tid; i < 64 * 256; i += 256) {
    int k = i >> 8, nn = i & 255;
    Wl[k][nn] = Wdt[(size_t)k * 1536 + n0 + nn];
  }
  for (int i = tid; i < 32 * 64; i += 256) {
    int mm = i >> 6, k = i & 63;
    Xl[mm][k] = xdbl[(size_t)(m0 + mm) * 1664 + 64 + k];   // delta_in cols 64..127
  }
  __syncthreads();
  float bv = bdt[n0 + tid];
  for (int mm = 0; mm < 32; ++mm) {
    float acc = bv;
#pragma unroll
    for (int k = 0; k < 64; ++k) acc = fmaf(Xl[mm][k], Wl[k][tid], acc);
    float sp = fmaxf(acc, 0.f) + log1pf(__expf(-fabsf(acc)));  // stable softplus
    delta[(size_t)(m0 + mm) * 1536 + n0 + tid] = fminf(sp, 10.f);
  }
}

// ---------- selective scan: wave per (b,d), lane = state s ----------
__global__ __launch_bounds__(256)
void scan_kernel(const float* __restrict__ xdbl, const float* __restrict__ delta,
                 const float* __restrict__ xs, const float* __restrict__ sres,
                 const float* __restrict__ A_log, const float* __restrict__ Dp,
                 ushort_t* __restrict__ ybf) {
  const int lane = threadIdx.x & 63;
  const int wave = (blockIdx.x << 2) + (threadIdx.x >> 6);   // 0..3071
  const int b = wave / 1536;
  const int d = wave - b * 1536;
  const float Aval = -__expf(A_log[d * 64 + lane]);
  const float dp = Dp[d];
  const size_t r0 = (size_t)b * 1024;
  const float* dptr = delta + r0 * 1536 + d;
  const float* xptr = xs    + r0 * 1536 + d;
  const float* rptr = sres  + r0 * 1536 + d;
  const float* Bptr = xdbl  + r0 * 1664 + lane;        // B_sel cols 0..63
  const float* Cptr = xdbl  + r0 * 1664 + 128 + d;     // C_sel cols 128..1663
  ushort_t* yptr = ybf + r0 * 1536 + d;

  float h = 0.f;
  float dt = dptr[0], xt = xptr[0], rt = rptr[0], Bt = Bptr[0], Ct = Cptr[0];
  for (int t = 0; t < 1024; ++t) {
    float dt2 = 0.f, xt2 = 0.f, rt2 = 0.f, Bt2 = 0.f, Ct2 = 0.f;
    if (t < 1023) {   // prefetch next step
      dt2 = dptr[1536]; xt2 = xptr[1536]; rt2 = rptr[1536];
      Bt2 = Bptr[1664]; Ct2 = Cptr[1664];
      dptr += 1536; xptr += 1536; rptr += 1536; Bptr += 1664; Cptr += 1664;
    }
    float dA = __expf(dt * Aval);
    h = fmaf(dA, h, dt * xt * Bt);
    float s = wave_sum64(h);
    if (lane == 63) {
      float y = Ct * s;
      yptr[0] = f2bf((y + xt * dp) * rt);   // fused: (+xs*Dp) * silu(res)
    }
    yptr += 1536;
    dt = dt2; xt = xt2; rt = rt2; Bt = Bt2; Ct = Ct2;
  }
}

// ---------- LayerNorm (row = 768) ----------
__global__ __launch_bounds__(256)
void ln_kernel(const float* __restrict__ in, const float* __restrict__ g,
               const float* __restrict__ be, float* __restrict__ outp) {
  const int row = blockIdx.x, tid = threadIdx.x;
  const float* p = in + (size_t)row * 768;
  float v0 = p[tid], v1 = p[tid + 256], v2 = p[tid + 512];
  __shared__ float sb[4];
  const int wid = tid >> 6;
  float s = wave_sum64(v0 + v1 + v2);
  if ((tid & 63) == 63) sb[wid] = s;
  __syncthreads();
  float mu = (sb[0] + sb[1] + sb[2] + sb[3]) * (1.f / 768.f);
  __syncthreads();
  float d0 = v0 - mu, d1 = v1 - mu, d2 = v2 - mu;
  float q = wave_sum64(d0 * d0 + d1 * d1 + d2 * d2);
  if ((tid & 63) == 63) sb[wid] = q;
  __syncthreads();
  float var = (sb[0] + sb[1] + sb[2] + sb[3]) * (1.f / 768.f);
  float inv = rsqrtf(var + 1e-5f);
  float* po = outp + (size_t)row * 768;
  po[tid]       = d0 * inv * g[tid]       + be[tid];
  po[tid + 256] = d1 * inv * g[tid + 256] + be[tid + 256];
  po[tid + 512] = d2 * inv * g[tid + 512] + be[tid + 512];
}

// ---------- launch ----------
extern "C" void kernel_launch(void* const* d_in, const int* in_sizes, int n_in,
                              void* d_out, int out_size, void* d_ws, size_t ws_size,
                              hipStream_t stream) {
  (void)in_sizes; (void)n_in; (void)out_size; (void)ws_size;
  const float* x     = (const float*)d_in[0];
  const float* W_in  = (const float*)d_in[1];
  const float* W_x   = (const float*)d_in[2];
  const float* W_dt  = (const float*)d_in[3];
  const float* b_dt  = (const float*)d_in[4];
  const float* A_log = (const float*)d_in[5];
  const float* Dp    = (const float*)d_in[6];
  const float* W_out = (const float*)d_in[7];
  const float* ln_g  = (const float*)d_in[8];
  const float* ln_b  = (const float*)d_in[9];
  float* out = (float*)d_out;
  char* ws = (char*)d_ws;

  ushort_t* xbf   = (ushort_t*)(ws + 0);          // 2048x768 bf16
  ushort_t* WinT  = (ushort_t*)(ws + 3145728);    // 3072x768 bf16
  ushort_t* WxT   = (ushort_t*)(ws + 7864320);    // 1664x1536 bf16
  ushort_t* WoutT = (ushort_t*)(ws + 12976128);   // 768x1536 bf16
  float*    xs_f  = (float*)   (ws + 15335424);   // 2048x1536 f32
  ushort_t* xs_bf = (ushort_t*)(ws + 27918336);   // 2048x1536 bf16
  float*    sresp = (float*)   (ws + 34209792);   // 2048x1536 f32 (silu(res))
  float*    xdbl  = (float*)   (ws + 46792704);   // 2048x1664 f32
  float*    dlt   = (float*)   (ws + 60424192);   // 2048x1536 f32
  ushort_t* ybf   = (ushort_t*)(ws + 73007104);   // 2048x1536 bf16
  float*    otmp  = (float*)   (ws + 79298560);   // 2048x768 f32

  conv_f32_bf16<<<1536, 256, 0, stream>>>(x, xbf);
  transpose_kernel<<<dim3(96, 24), 256, 0, stream>>>(W_in, WinT, 768, 3072);
  transpose_kernel<<<dim3(52, 48), 256, 0, stream>>>(W_x, WxT, 1536, 1664);
  transpose_kernel<<<dim3(24, 48), 256, 0, stream>>>(W_out, WoutT, 1536, 768);

  gemm_bf16<0><<<dim3(24, 16), 256, 0, stream>>>(xbf, WinT, 768, xs_f, xs_bf, sresp, nullptr);
  gemm_bf16<1><<<dim3(13, 16), 256, 0, stream>>>(xs_bf, WxT, 1536, xdbl, nullptr, nullptr, nullptr);
  dt_gemm<<<dim3(6, 64), 256, 0, stream>>>(xdbl, W_dt, b_dt, dlt);
  scan_kernel<<<768, 256, 0, stream>>>(xdbl, dlt, xs_f, sresp, A_log, Dp, ybf);
  gemm_bf16<2><<<dim3(6, 16), 256, 0, stream>>>(ybf, WoutT, 1536, otmp, nullptr, nullptr, x);
  ln_kernel<<<2048, 256, 0, stream>>>(otmp, ln_g, ln_b, out);
}

// Round 2
// 284.768 us; speedup vs baseline: 2.1197x; 2.1197x over previous
//
#include <hip/hip_runtime.h>

typedef __bf16 bf16x8 __attribute__((ext_vector_type(8)));
typedef short short8 __attribute__((ext_vector_type(8)));
typedef float f32x4 __attribute__((ext_vector_type(4)));
typedef unsigned short ushort_t;

// ---------- helpers ----------
__device__ __forceinline__ ushort_t f2bf(float f) {
  union { float f; unsigned u; } v; v.f = f;
  unsigned r = v.u + 0x7fffu + ((v.u >> 16) & 1u);   // RNE
  return (ushort_t)(r >> 16);
}

__device__ __forceinline__ void g2lds16(const void* g, void* l) {
  __builtin_amdgcn_global_load_lds(
      (const __attribute__((address_space(1))) void*)g,
      (__attribute__((address_space(3))) void*)l, 16, 0, 0);
}

__device__ __forceinline__ float rlane(float v, int l) {
  return __int_as_float(__builtin_amdgcn_readlane(__float_as_int(v), l));
}

template<int CTRL>
__device__ __forceinline__ float dpp_step(float x) {
  int t = __builtin_amdgcn_update_dpp(0, __float_as_int(x), CTRL, 0xf, 0xf, false);
  return x + __int_as_float(t);
}
// full 64-lane sum; result valid on lane 63
__device__ __forceinline__ float wave_sum64(float v) {
  v = dpp_step<0x111>(v);  // row_shr:1
  v = dpp_step<0x112>(v);  // row_shr:2
  v = dpp_step<0x114>(v);  // row_shr:4
  v = dpp_step<0x118>(v);  // row_shr:8
  v = dpp_step<0x142>(v);  // row_bcast:15
  v = dpp_step<0x143>(v);  // row_bcast:31
  return v;
}

// ---------- conversion / transpose ----------
__global__ __launch_bounds__(256) void conv_f32_bf16(const float* __restrict__ in,
                                                     ushort_t* __restrict__ outp) {
  int i = (blockIdx.x * 256 + threadIdx.x) * 4;
  float4 v = *(const float4*)(in + i);
  union { ushort_t u[4]; uint2 v2; } o;
  o.u[0] = f2bf(v.x); o.u[1] = f2bf(v.y); o.u[2] = f2bf(v.z); o.u[3] = f2bf(v.w);
  *(uint2*)(outp + i) = o.v2;
}

// W [K][N] f32 -> Wt [N][K] bf16
__global__ __launch_bounds__(256) void transpose_kernel(const float* __restrict__ W,
                                                        ushort_t* __restrict__ Wt,
                                                        int K, int N) {
  __shared__ float tile[32][33];
  const int n0 = blockIdx.x * 32, k0 = blockIdx.y * 32;
  const int tx = threadIdx.x & 31, ty = threadIdx.x >> 5;  // 32x8
#pragma unroll
  for (int r = 0; r < 32; r += 8)
    tile[ty + r][tx] = W[(size_t)(k0 + ty + r) * N + n0 + tx];
  __syncthreads();
#pragma unroll
  for (int r = 0; r < 32; r += 8)
    Wt[(size_t)(n0 + ty + r) * K + k0 + tx] = f2bf(tile[tx][ty + r]);
}

// ---------- bf16 MFMA GEMM (m97 structure: 128x128 tile, BK=32, 4 waves) ----------
template<int MODE>
__global__ __launch_bounds__(256)
void gemm_bf16(const ushort_t* __restrict__ A, const ushort_t* __restrict__ Bt,
               const int K, float* __restrict__ out0, ushort_t* __restrict__ out1,
               float* __restrict__ out2, const float* __restrict__ resid) {
  __shared__ __align__(16) ushort_t Asl[128 * 32];
  __shared__ __align__(16) ushort_t Bsl[128 * 32];
  const int tid = threadIdx.x;
  const int lane = tid & 63;
  const int wid = tid >> 6;
  const int wm = wid >> 1, wn = wid & 1;
  const int lr = lane & 15, lk = lane >> 4;
  const int bm = blockIdx.y, bn = blockIdx.x;
  const ushort_t* Ab = A + (size_t)bm * 128 * K;
  const ushort_t* Bb = Bt + (size_t)bn * 128 * K;

  f32x4 acc[4][4];
#pragma unroll
  for (int i = 0; i < 4; ++i)
#pragma unroll
    for (int j = 0; j < 4; ++j) acc[i][j] = (f32x4){0.f, 0.f, 0.f, 0.f};

  for (int k0 = 0; k0 < K; k0 += 32) {
#pragma unroll
    for (int it = 0; it < 2; ++it) {
      const int cb = ((it << 2) + wid) << 6;   // wave-uniform chunk base
      const int ch = cb + lane;
      const int row = ch >> 2;
      const int c8 = (ch & 3) << 3;
      g2lds16(Ab + (size_t)row * K + k0 + c8, Asl + (size_t)cb * 8);
      g2lds16(Bb + (size_t)row * K + k0 + c8, Bsl + (size_t)cb * 8);
    }
    __syncthreads();
    short8 av[4], bv[4];
#pragma unroll
    for (int i = 0; i < 4; ++i)
      av[i] = *(const short8*)(Asl + ((wm * 64 + i * 16 + lr) * 32 + lk * 8));
#pragma unroll
    for (int j = 0; j < 4; ++j)
      bv[j] = *(const short8*)(Bsl + ((wn * 64 + j * 16 + lr) * 32 + lk * 8));
#pragma unroll
    for (int i = 0; i < 4; ++i)
#pragma unroll
      for (int j = 0; j < 4; ++j)
        acc[i][j] = __builtin_amdgcn_mfma_f32_16x16x32_bf16(
            __builtin_bit_cast(bf16x8, av[i]), __builtin_bit_cast(bf16x8, bv[j]),
            acc[i][j], 0, 0, 0);
    __syncthreads();
  }

  const int mb = bm * 128 + wm * 64 + (lane >> 4) * 4;
  const int nb = bn * 128 + wn * 64 + (lane & 15);
#pragma unroll
  for (int i = 0; i < 4; ++i) {
#pragma unroll
    for (int j = 0; j < 4; ++j) {
      const int n = nb + j * 16;
#pragma unroll
      for (int r = 0; r < 4; ++r) {
        const int m = mb + i * 16 + r;
        float v = acc[i][j][r];
        if (MODE == 0) {
          float sv = v / (1.f + __expf(-v));   // silu
          if (n < 1536) {
            out0[(size_t)m * 1536 + n] = sv;
            out1[(size_t)m * 1536 + n] = f2bf(sv);
          } else {
            out2[(size_t)m * 1536 + (n - 1536)] = sv;
          }
        } else if (MODE == 1) {
          out0[(size_t)m * 1664 + n] = v;
        } else {
          const size_t id = (size_t)m * 768 + n;
          out0[id] = v + resid[id];
        }
      }
    }
  }
}

// ---------- delta GEMM (K=64) + softplus + clamp ----------
__global__ __launch_bounds__(256)
void dt_gemm(const float* __restrict__ xdbl, const float* __restrict__ Wdt,
             const float* __restrict__ bdt, float* __restrict__ delta) {
  __shared__ float Wl[64][256];
  __shared__ float Xl[32][64];
  const int tid = threadIdx.x;
  const int n0 = blockIdx.x << 8;
  const int m0 = blockIdx.y << 5;
  for (int i = tid; i < 64 * 256; i += 256) {
    int k = i >> 8, nn = i & 255;
    Wl[k][nn] = Wdt[(size_t)k * 1536 + n0 + nn];
  }
  for (int i = tid; i < 32 * 64; i += 256) {
    int mm = i >> 6, k = i & 63;
    Xl[mm][k] = xdbl[(size_t)(m0 + mm) * 1664 + 64 + k];   // delta_in cols 64..127
  }
  __syncthreads();
  float bv = bdt[n0 + tid];
  for (int mm = 0; mm < 32; ++mm) {
    float acc = bv;
#pragma unroll
    for (int k = 0; k < 64; ++k) acc = fmaf(Xl[mm][k], Wl[k][tid], acc);
    float sp = fmaxf(acc, 0.f) + log1pf(__expf(-fabsf(acc)));  // stable softplus
    delta[(size_t)(m0 + mm) * 1536 + n0 + tid] = fminf(sp, 10.f);
  }
}

// ---------- selective scan: wave per (b,d), lane = state s ----------
// Chunked: 16 chunks of 64 timesteps. Per chunk: coalesced per-lane gathers of
// the 4 scalar streams (lane = t), B_sel tile double-buffered in LDS via
// global_load_lds; per-step broadcasts via v_readlane (SGPR, unroll-literal).
__global__ __launch_bounds__(256)
void scan_kernel(const float* __restrict__ xdbl, const float* __restrict__ delta,
                 const float* __restrict__ xs, const float* __restrict__ sres,
                 const float* __restrict__ A_log, const float* __restrict__ Dp,
                 ushort_t* __restrict__ ybf) {
  __shared__ __align__(16) float Bl[2][64 * 64];
  const int tid = threadIdx.x;
  const int lane = tid & 63;
  const int wid = tid >> 6;
  const int bi = blockIdx.x;              // 0..767
  const int b = (bi >= 384) ? 1 : 0;
  const int d = (bi - b * 384) * 4 + wid; // 0..1535
  const float Aval = -__expf(A_log[d * 64 + lane]);
  const float dp = Dp[d];
  const size_t r0 = (size_t)b * 1024;

  // B-tile staging: 64 t x 64 s floats = 16 KB, via global_load_lds width 16
  auto stageB = [&](int t0, int buf) {
#pragma unroll
    for (int it = 0; it < 4; ++it) {
      const int q = it * 256 + tid;        // float4 index; wave-uniform base + lane*16
      g2lds16(xdbl + (r0 + t0 + (q >> 4)) * 1664 + ((q & 15) << 2),
              &Bl[buf][q << 2]);
    }
  };

  // per-lane chunk gathers (lane = t within chunk)
  auto g_dt = [&](int t0) { return delta[(r0 + t0 + lane) * 1536 + d]; };
  auto g_xs = [&](int t0) { return xs   [(r0 + t0 + lane) * 1536 + d]; };
  auto g_rs = [&](int t0) { return sres [(r0 + t0 + lane) * 1536 + d]; };
  auto g_Ct = [&](int t0) { return xdbl [(r0 + t0 + lane) * 1664 + 128 + d]; };

  stageB(0, 0);
  float dtv = g_dt(0), xtv = g_xs(0), rtv = g_rs(0), Ctv = g_Ct(0);
  float dxv = dtv * xtv;

  float h = 0.f;
  for (int c = 0; c < 16; ++c) {
    __syncthreads();   // drains stage(c) vmcnt; buf[c&1] ready; all waves aligned
    float ndt = dtv, nxt = xtv, nrt = rtv, nCt = Ctv;
    if (c < 15) {
      stageB((c + 1) << 6, (c + 1) & 1);   // hidden under this chunk's compute
      const int t0n = (c + 1) << 6;
      ndt = g_dt(t0n); nxt = g_xs(t0n); nrt = g_rs(t0n); nCt = g_Ct(t0n);
    }
    const float* Bb = Bl[c & 1];
    float yacc = 0.f;
#pragma unroll
    for (int tt = 0; tt < 64; ++tt) {
      float dts = rlane(dtv, tt);
      float dxs = rlane(dxv, tt);
      float dA = __expf(dts * Aval);
      float bs = Bb[tt * 64 + lane];
      h = fmaf(dA, h, dxs * bs);
      float S = wave_sum64(h);
      float Sb = rlane(S, 63);
      yacc = (lane == tt) ? Sb : yacc;
    }
    // chunk epilogue: fused (y + xs*Dp) * silu(res), lane = t
    const int tg = (c << 6) + lane;
    ybf[(r0 + tg) * 1536 + d] = f2bf((Ctv * yacc + xtv * dp) * rtv);
    dtv = ndt; xtv = nxt; rtv = nrt; Ctv = nCt;
    dxv = dtv * xtv;
  }
}

// ---------- LayerNorm (row = 768) ----------
__global__ __launch_bounds__(256)
void ln_kernel(const float* __restrict__ in, const float* __restrict__ g,
               const float* __restrict__ be, float* __restrict__ outp) {
  const int row = blockIdx.x, tid = threadIdx.x;
  const float* p = in + (size_t)row * 768;
  float v0 = p[tid], v1 = p[tid + 256], v2 = p[tid + 512];
  __shared__ float sb[4];
  const int wid = tid >> 6;
  float s = wave_sum64(v0 + v1 + v2);
  if ((tid & 63) == 63) sb[wid] = s;
  __syncthreads();
  float mu = (sb[0] + sb[1] + sb[2] + sb[3]) * (1.f / 768.f);
  __syncthreads();
  float d0 = v0 - mu, d1 = v1 - mu, d2 = v2 - mu;
  float q = wave_sum64(d0 * d0 + d1 * d1 + d2 * d2);
  if ((tid & 63) == 63) sb[wid] = q;
  __syncthreads();
  float var = (sb[0] + sb[1] + sb[2] + sb[3]) * (1.f / 768.f);
  float inv = rsqrtf(var + 1e-5f);
  float* po = outp + (size_t)row * 768;
  po[tid]       = d0 * inv * g[tid]       + be[tid];
  po[tid + 256] = d1 * inv * g[tid + 256] + be[tid + 256];
  po[tid + 512] = d2 * inv * g[tid + 512] + be[tid + 512];
}

// ---------- launch ----------
extern "C" void kernel_launch(void* const* d_in, const int* in_sizes, int n_in,
                              void* d_out, int out_size, void* d_ws, size_t ws_size,
                              hipStream_t stream) {
  (void)in_sizes; (void)n_in; (void)out_size; (void)ws_size;
  const float* x     = (const float*)d_in[0];
  const float* W_in  = (const float*)d_in[1];
  const float* W_x   = (const float*)d_in[2];
  const float* W_dt  = (const float*)d_in[3];
  const float* b_dt  = (const float*)d_in[4];
  const float* A_log = (const float*)d_in[5];
  const float* Dp    = (const float*)d_in[6];
  const float* W_out = (const float*)d_in[7];
  const float* ln_g  = (const float*)d_in[8];
  const float* ln_b  = (const float*)d_in[9];
  float* out = (float*)d_out;
  char* ws = (char*)d_ws;

  ushort_t* xbf   = (ushort_t*)(ws + 0);          // 2048x768 bf16
  ushort_t* WinT  = (ushort_t*)(ws + 3145728);    // 3072x768 bf16
  ushort_t* WxT   = (ushort_t*)(ws + 7864320);    // 1664x1536 bf16
  ushort_t* WoutT = (ushort_t*)(ws + 12976128);   // 768x1536 bf16
  float*    xs_f  = (float*)   (ws + 15335424);   // 2048x1536 f32
  ushort_t* xs_bf = (ushort_t*)(ws + 27918336);   // 2048x1536 bf16
  float*    sresp = (float*)   (ws + 34209792);   // 2048x1536 f32 (silu(res))
  float*    xdbl  = (float*)   (ws + 46792704);   // 2048x1664 f32
  float*    dlt   = (float*)   (ws + 60424192);   // 2048x1536 f32
  ushort_t* ybf   = (ushort_t*)(ws + 73007104);   // 2048x1536 bf16
  float*    otmp  = (float*)   (ws + 79298560);   // 2048x768 f32

  conv_f32_bf16<<<1536, 256, 0, stream>>>(x, xbf);
  transpose_kernel<<<dim3(96, 24), 256, 0, stream>>>(W_in, WinT, 768, 3072);
  transpose_kernel<<<dim3(52, 48), 256, 0, stream>>>(W_x, WxT, 1536, 1664);
  transpose_kernel<<<dim3(24, 48), 256, 0, stream>>>(W_out, WoutT, 1536, 768);

  gemm_bf16<0><<<dim3(24, 16), 256, 0, stream>>>(xbf, WinT, 768, xs_f, xs_bf, sresp, nullptr);
  gemm_bf16<1><<<dim3(13, 16), 256, 0, stream>>>(xs_bf, WxT, 1536, xdbl, nullptr, nullptr, nullptr);
  dt_gemm<<<dim3(6, 64), 256, 0, stream>>>(xdbl, W_dt, b_dt, dlt);
  scan_kernel<<<768, 256, 0, stream>>>(xdbl, dlt, xs_f, sresp, A_log, Dp, ybf);
  gemm_bf16<2><<<dim3(6, 16), 256, 0, stream>>>(ybf, WoutT, 1536, otmp, nullptr, nullptr, x);
  ln_kernel<<<2048, 256, 0, stream>>>(otmp, ln_g, ln_b, out);
}